// Round 12
// baseline (189.048 us; speedup 1.0000x reference)
//
#include <hip/hip_runtime.h>
#include <cstdint>
#include <cstddef>

// BinSAGE: 2-layer GraphSAGE with sign-binarized weights. MFMA bf16 + bucket-sort CSR.
// N=50000 nodes, E=800000 edges, dims 96 -> 128 -> 64.
//   count_prep (1 dispatch): 64 blocks histogram dst>>8 into partials; other
//     blocks build S1t/S2t sign matrices + xb = bf16(x).
//   bucket_scan (1 block) -> bases/cursors; bucket_scatter -> packed bucketBuf;
//   bucket_build -> rowptr + adj16 (u16, dst-sorted CSR).
//   agg1: mean of xb over in-edges -> AGGb bf16 [N,96]
//   gemm12 (fused MFMA, B staged in LDS): [AGGb|xb] @ S1t^T -> relu -> H (LDS)
//                                         H @ S2t^T -> T2b bf16 + R2 f32
//   final: out = inv_deg * segsum(T2b[src]) + R2
// R11 lesson: gathers are concurrency-limited (only ~16 lines in flight/CU at
// ~200cyc L2 latency); fix is DEEPER batches, not ownership changes. R12:
// 8 edges per subgroup iteration, indices via 4 packed dword loads.
// R9 lesson: GEMM B must be LDS-staged. R7 lesson: AGGb disjoint from T2b/R2.

#define N_NODES 50000
#define IN_DIM 96
#define HID 128
#define OUT_DIM 64
#define CNT_BLOCKS 64

typedef __attribute__((ext_vector_type(8))) short bf16x8;
typedef __attribute__((ext_vector_type(4))) float f32x4;

static inline size_t alignUp(size_t v, size_t a) { return (v + a - 1) & ~(a - 1); }

__device__ __forceinline__ uint16_t f2bf(float f) {
  uint32_t u = __float_as_uint(f);
  return (uint16_t)((u + 0x7FFF + ((u >> 16) & 1)) >> 16);
}
__device__ __forceinline__ float bflo(uint32_t v) { return __uint_as_float(v << 16); }
__device__ __forceinline__ float bfhi(uint32_t v) { return __uint_as_float(v & 0xFFFF0000u); }
__device__ __forceinline__ uint16_t sgnbf(float w) {
  return (w > 0.f) ? (uint16_t)0x3F80 : ((w < 0.f) ? (uint16_t)0xBF80 : (uint16_t)0);
}

#define NS1 (128 * 192)
#define NS2 (128 * 128)

// ---------------- merged: bucket count (64 partial rows) + prep ----------------
__global__ __launch_bounds__(256) void count_prep_kernel(const int* __restrict__ dst,
    int* __restrict__ bucketPart, int E,
    const float* __restrict__ x,
    const float* __restrict__ w1l, const float* __restrict__ w1r,
    const float* __restrict__ w2l, const float* __restrict__ w2r,
    uint16_t* __restrict__ S1t, uint16_t* __restrict__ S2t,
    uint16_t* __restrict__ xb, int total4) {
  __shared__ int h[256];
  const int t = threadIdx.x;
  if (blockIdx.x < CNT_BLOCKS) {
    h[t] = 0;
    __syncthreads();
    const int stride = CNT_BLOCKS * 256;
    for (int i = blockIdx.x * 256 + t; i < E; i += stride)
      atomicAdd(&h[dst[i] >> 8], 1);
    __syncthreads();
    bucketPart[blockIdx.x * 256 + t] = h[t];
  } else {
    const int idx = (blockIdx.x - CNT_BLOCKS) * 256 + t;
    if (idx < NS1) {
      int n = idx / 192, k = idx - n * 192;
      float w = (k < 96) ? w1l[n * 96 + k] : w1r[n * 96 + (k - 96)];
      S1t[idx] = sgnbf(w);
    } else if (idx < NS1 + NS2) {
      int i2 = idx - NS1;
      int n = i2 >> 7, k = i2 & 127;
      float w = (n < 64) ? w2l[n * 128 + k] : w2r[(n - 64) * 128 + k];
      S2t[i2] = sgnbf(w);
    } else {
      int i = idx - NS1 - NS2;
      if (i < total4) {
        float4 v = *(const float4*)(x + (size_t)i * 4);
        uint32_t p0 = (uint32_t)f2bf(v.x) | ((uint32_t)f2bf(v.y) << 16);
        uint32_t p1 = (uint32_t)f2bf(v.z) | ((uint32_t)f2bf(v.w) << 16);
        *(uint2*)(xb + (size_t)i * 4) = make_uint2(p0, p1);
      }
    }
  }
}

// 1 block: column-sum 64 partial rows -> scan -> bases/cursors, rowptr[N]=E.
__global__ __launch_bounds__(256) void bucket_scan_kernel(const int* __restrict__ bucketPart,
    int* __restrict__ bucketBase, int* __restrict__ bucketCursor, int* __restrict__ rowptr,
    int nB, int N) {
  __shared__ int smem[256];
  const int t = threadIdx.x;
  int v = 0;
  for (int b = 0; b < CNT_BLOCKS; ++b) v += bucketPart[b * 256 + t];
  if (t >= nB) v = 0;
  smem[t] = v;
  __syncthreads();
  for (int off = 1; off < 256; off <<= 1) {
    int u = (t >= off) ? smem[t - off] : 0;
    __syncthreads();
    smem[t] += u;
    __syncthreads();
  }
  if (t < nB) {
    const int excl = smem[t] - v;
    bucketBase[t] = excl;
    bucketCursor[t] = excl;
  }
  if (t == 255) {
    bucketBase[nB] = smem[255];
    rowptr[N] = smem[255];
  }
}

#define SCAT_CHUNK 2048
__global__ __launch_bounds__(256) void bucket_scatter_kernel(const int* __restrict__ src,
    const int* __restrict__ dst, int* __restrict__ bucketCursor,
    uint32_t* __restrict__ bucketBuf, int E) {
  __shared__ int h[256];
  __shared__ int g[256];
  __shared__ int c[256];
  const int t = threadIdx.x;
  const int base = blockIdx.x * SCAT_CHUNK;
  const int end = min(base + SCAT_CHUNK, E);
  h[t] = 0;
  __syncthreads();
  for (int i = base + t; i < end; i += 256)
    atomicAdd(&h[dst[i] >> 8], 1);
  __syncthreads();
  if (h[t]) g[t] = atomicAdd(&bucketCursor[t], h[t]);
  c[t] = 0;
  __syncthreads();
  for (int i = base + t; i < end; i += 256) {
    const int d = dst[i];
    const int b = d >> 8;
    const int ticket = atomicAdd(&c[b], 1);
    bucketBuf[g[b] + ticket] = (uint32_t)src[i] | ((uint32_t)(d & 255) << 16);
  }
}

__global__ __launch_bounds__(256) void bucket_build_kernel(const uint32_t* __restrict__ bucketBuf,
    const int* __restrict__ bucketBase, int* __restrict__ rowptr,
    uint16_t* __restrict__ adj16, int N) {
  __shared__ int h[256];
  __shared__ int s[256];
  __shared__ int cur[256];
  const int t = threadIdx.x;
  const int b = blockIdx.x;
  const int nodeBase = b << 8;
  const int beg = bucketBase[b], end = bucketBase[b + 1];
  const int m = end - beg;
  h[t] = 0;
  __syncthreads();
  for (int i = t; i < m; i += 256)
    atomicAdd(&h[(bucketBuf[beg + i] >> 16) & 255], 1);
  __syncthreads();
  const int d = h[t];
  s[t] = d;
  __syncthreads();
  for (int off = 1; off < 256; off <<= 1) {
    int u = (t >= off) ? s[t - off] : 0;
    __syncthreads();
    s[t] += u;
    __syncthreads();
  }
  const int excl = s[t] - d;
  const int node = nodeBase + t;
  if (node < N) rowptr[node] = beg + excl;
  cur[t] = excl;
  __syncthreads();
  for (int i = t; i < m; i += 256) {
    const uint32_t u = bucketBuf[beg + i];
    const int ld = (u >> 16) & 255;
    const int ticket = atomicAdd(&cur[ld], 1);
    adj16[beg + ticket] = (uint16_t)(u & 0xFFFFu);
  }
}

// ---------------- gathers: subgroup(16)=node, 8-edge batches ----------------
__global__ __launch_bounds__(256) void agg1_kernel(const uint16_t* __restrict__ xb,
    const uint16_t* __restrict__ adj16, const int* __restrict__ rowptr,
    uint16_t* __restrict__ AGGb, int nNodes) {
  const int sg = threadIdx.x >> 4;
  const int j = threadIdx.x & 15;
  const int n = blockIdx.x * 16 + sg;
  if (n >= nNodes) return;
  const int beg = rowptr[n], end = rowptr[n + 1];
  const bool act = j < 12;
  const int foff = j * 8;
  float a0 = 0.f, a1 = 0.f, a2 = 0.f, a3 = 0.f, a4 = 0.f, a5 = 0.f, a6 = 0.f, a7 = 0.f;

  int e = beg;
  // head: make e even so packed dword index loads are 4B-aligned
  if ((e & 1) && e < end) {
    const int s = adj16[e];
    uint4 v = make_uint4(0u,0u,0u,0u);
    if (act) v = *(const uint4*)(xb + (size_t)s * IN_DIM + foff);
    a0 += bflo(v.x); a1 += bfhi(v.x); a2 += bflo(v.y); a3 += bfhi(v.y);
    a4 += bflo(v.z); a5 += bfhi(v.z); a6 += bflo(v.w); a7 += bfhi(v.w);
    ++e;
  }
  for (; e + 8 <= end; e += 8) {
    const uint32_t p0 = *(const uint32_t*)(adj16 + e);
    const uint32_t p1 = *(const uint32_t*)(adj16 + e + 2);
    const uint32_t p2 = *(const uint32_t*)(adj16 + e + 4);
    const uint32_t p3 = *(const uint32_t*)(adj16 + e + 6);
    const int s0 = p0 & 0xFFFF, s1 = p0 >> 16;
    const int s2 = p1 & 0xFFFF, s3 = p1 >> 16;
    const int s4 = p2 & 0xFFFF, s5 = p2 >> 16;
    const int s6 = p3 & 0xFFFF, s7 = p3 >> 16;
    uint4 v0 = make_uint4(0u,0u,0u,0u), v1 = v0, v2 = v0, v3 = v0;
    uint4 v4 = v0, v5 = v0, v6 = v0, v7 = v0;
    if (act) {
      v0 = *(const uint4*)(xb + (size_t)s0 * IN_DIM + foff);
      v1 = *(const uint4*)(xb + (size_t)s1 * IN_DIM + foff);
      v2 = *(const uint4*)(xb + (size_t)s2 * IN_DIM + foff);
      v3 = *(const uint4*)(xb + (size_t)s3 * IN_DIM + foff);
      v4 = *(const uint4*)(xb + (size_t)s4 * IN_DIM + foff);
      v5 = *(const uint4*)(xb + (size_t)s5 * IN_DIM + foff);
      v6 = *(const uint4*)(xb + (size_t)s6 * IN_DIM + foff);
      v7 = *(const uint4*)(xb + (size_t)s7 * IN_DIM + foff);
    }
    __builtin_amdgcn_sched_barrier(0);
    a0 += (bflo(v0.x) + bflo(v1.x) + bflo(v2.x) + bflo(v3.x))
        + (bflo(v4.x) + bflo(v5.x) + bflo(v6.x) + bflo(v7.x));
    a1 += (bfhi(v0.x) + bfhi(v1.x) + bfhi(v2.x) + bfhi(v3.x))
        + (bfhi(v4.x) + bfhi(v5.x) + bfhi(v6.x) + bfhi(v7.x));
    a2 += (bflo(v0.y) + bflo(v1.y) + bflo(v2.y) + bflo(v3.y))
        + (bflo(v4.y) + bflo(v5.y) + bflo(v6.y) + bflo(v7.y));
    a3 += (bfhi(v0.y) + bfhi(v1.y) + bfhi(v2.y) + bfhi(v3.y))
        + (bfhi(v4.y) + bfhi(v5.y) + bfhi(v6.y) + bfhi(v7.y));
    a4 += (bflo(v0.z) + bflo(v1.z) + bflo(v2.z) + bflo(v3.z))
        + (bflo(v4.z) + bflo(v5.z) + bflo(v6.z) + bflo(v7.z));
    a5 += (bfhi(v0.z) + bfhi(v1.z) + bfhi(v2.z) + bfhi(v3.z))
        + (bfhi(v4.z) + bfhi(v5.z) + bfhi(v6.z) + bfhi(v7.z));
    a6 += (bflo(v0.w) + bflo(v1.w) + bflo(v2.w) + bflo(v3.w))
        + (bflo(v4.w) + bflo(v5.w) + bflo(v6.w) + bflo(v7.w));
    a7 += (bfhi(v0.w) + bfhi(v1.w) + bfhi(v2.w) + bfhi(v3.w))
        + (bfhi(v4.w) + bfhi(v5.w) + bfhi(v6.w) + bfhi(v7.w));
  }
  if (e + 4 <= end) {
    const uint32_t p0 = *(const uint32_t*)(adj16 + e);
    const uint32_t p1 = *(const uint32_t*)(adj16 + e + 2);
    const int s0 = p0 & 0xFFFF, s1 = p0 >> 16;
    const int s2 = p1 & 0xFFFF, s3 = p1 >> 16;
    uint4 v0 = make_uint4(0u,0u,0u,0u), v1 = v0, v2 = v0, v3 = v0;
    if (act) {
      v0 = *(const uint4*)(xb + (size_t)s0 * IN_DIM + foff);
      v1 = *(const uint4*)(xb + (size_t)s1 * IN_DIM + foff);
      v2 = *(const uint4*)(xb + (size_t)s2 * IN_DIM + foff);
      v3 = *(const uint4*)(xb + (size_t)s3 * IN_DIM + foff);
    }
    __builtin_amdgcn_sched_barrier(0);
    a0 += bflo(v0.x) + bflo(v1.x) + bflo(v2.x) + bflo(v3.x);
    a1 += bfhi(v0.x) + bfhi(v1.x) + bfhi(v2.x) + bfhi(v3.x);
    a2 += bflo(v0.y) + bflo(v1.y) + bflo(v2.y) + bflo(v3.y);
    a3 += bfhi(v0.y) + bfhi(v1.y) + bfhi(v2.y) + bfhi(v3.y);
    a4 += bflo(v0.z) + bflo(v1.z) + bflo(v2.z) + bflo(v3.z);
    a5 += bfhi(v0.z) + bfhi(v1.z) + bfhi(v2.z) + bfhi(v3.z);
    a6 += bflo(v0.w) + bflo(v1.w) + bflo(v2.w) + bflo(v3.w);
    a7 += bfhi(v0.w) + bfhi(v1.w) + bfhi(v2.w) + bfhi(v3.w);
    e += 4;
  }
  for (; e < end; ++e) {
    const int s = adj16[e];
    uint4 v = make_uint4(0u,0u,0u,0u);
    if (act) v = *(const uint4*)(xb + (size_t)s * IN_DIM + foff);
    a0 += bflo(v.x); a1 += bfhi(v.x); a2 += bflo(v.y); a3 += bfhi(v.y);
    a4 += bflo(v.z); a5 += bfhi(v.z); a6 += bflo(v.w); a7 += bfhi(v.w);
  }
  if (act) {
    const int d = end - beg;
    const float inv = 1.0f / (float)(d > 1 ? d : 1);
    uint4 o;
    o.x = (uint32_t)f2bf(a0 * inv) | ((uint32_t)f2bf(a1 * inv) << 16);
    o.y = (uint32_t)f2bf(a2 * inv) | ((uint32_t)f2bf(a3 * inv) << 16);
    o.z = (uint32_t)f2bf(a4 * inv) | ((uint32_t)f2bf(a5 * inv) << 16);
    o.w = (uint32_t)f2bf(a6 * inv) | ((uint32_t)f2bf(a7 * inv) << 16);
    *(uint4*)(AGGb + (size_t)n * IN_DIM + foff) = o;
  }
}

__global__ __launch_bounds__(256) void final_kernel(const uint16_t* __restrict__ T2b,
    const float* __restrict__ R2, const uint16_t* __restrict__ adj16,
    const int* __restrict__ rowptr, float* __restrict__ out, int nNodes) {
  const int sg = threadIdx.x >> 4;
  const int j = threadIdx.x & 15;
  const int n = blockIdx.x * 16 + sg;
  if (n >= nNodes) return;
  const int beg = rowptr[n], end = rowptr[n + 1];
  const int foff = j * 4;
  float a0 = 0.f, a1 = 0.f, a2 = 0.f, a3 = 0.f;

  int e = beg;
  if ((e & 1) && e < end) {
    const int s = adj16[e];
    const uint2 v = *(const uint2*)(T2b + (size_t)s * 64 + foff);
    a0 += bflo(v.x); a1 += bfhi(v.x); a2 += bflo(v.y); a3 += bfhi(v.y);
    ++e;
  }
  for (; e + 8 <= end; e += 8) {
    const uint32_t p0 = *(const uint32_t*)(adj16 + e);
    const uint32_t p1 = *(const uint32_t*)(adj16 + e + 2);
    const uint32_t p2 = *(const uint32_t*)(adj16 + e + 4);
    const uint32_t p3 = *(const uint32_t*)(adj16 + e + 6);
    const int s0 = p0 & 0xFFFF, s1 = p0 >> 16;
    const int s2 = p1 & 0xFFFF, s3 = p1 >> 16;
    const int s4 = p2 & 0xFFFF, s5 = p2 >> 16;
    const int s6 = p3 & 0xFFFF, s7 = p3 >> 16;
    const uint2 v0 = *(const uint2*)(T2b + (size_t)s0 * 64 + foff);
    const uint2 v1 = *(const uint2*)(T2b + (size_t)s1 * 64 + foff);
    const uint2 v2 = *(const uint2*)(T2b + (size_t)s2 * 64 + foff);
    const uint2 v3 = *(const uint2*)(T2b + (size_t)s3 * 64 + foff);
    const uint2 v4 = *(const uint2*)(T2b + (size_t)s4 * 64 + foff);
    const uint2 v5 = *(const uint2*)(T2b + (size_t)s5 * 64 + foff);
    const uint2 v6 = *(const uint2*)(T2b + (size_t)s6 * 64 + foff);
    const uint2 v7 = *(const uint2*)(T2b + (size_t)s7 * 64 + foff);
    __builtin_amdgcn_sched_barrier(0);
    a0 += (bflo(v0.x) + bflo(v1.x) + bflo(v2.x) + bflo(v3.x))
        + (bflo(v4.x) + bflo(v5.x) + bflo(v6.x) + bflo(v7.x));
    a1 += (bfhi(v0.x) + bfhi(v1.x) + bfhi(v2.x) + bfhi(v3.x))
        + (bfhi(v4.x) + bfhi(v5.x) + bfhi(v6.x) + bfhi(v7.x));
    a2 += (bflo(v0.y) + bflo(v1.y) + bflo(v2.y) + bflo(v3.y))
        + (bflo(v4.y) + bflo(v5.y) + bflo(v6.y) + bflo(v7.y));
    a3 += (bfhi(v0.y) + bfhi(v1.y) + bfhi(v2.y) + bfhi(v3.y))
        + (bfhi(v4.y) + bfhi(v5.y) + bfhi(v6.y) + bfhi(v7.y));
  }
  if (e + 4 <= end) {
    const uint32_t p0 = *(const uint32_t*)(adj16 + e);
    const uint32_t p1 = *(const uint32_t*)(adj16 + e + 2);
    const int s0 = p0 & 0xFFFF, s1 = p0 >> 16;
    const int s2 = p1 & 0xFFFF, s3 = p1 >> 16;
    const uint2 v0 = *(const uint2*)(T2b + (size_t)s0 * 64 + foff);
    const uint2 v1 = *(const uint2*)(T2b + (size_t)s1 * 64 + foff);
    const uint2 v2 = *(const uint2*)(T2b + (size_t)s2 * 64 + foff);
    const uint2 v3 = *(const uint2*)(T2b + (size_t)s3 * 64 + foff);
    __builtin_amdgcn_sched_barrier(0);
    a0 += bflo(v0.x) + bflo(v1.x) + bflo(v2.x) + bflo(v3.x);
    a1 += bfhi(v0.x) + bfhi(v1.x) + bfhi(v2.x) + bfhi(v3.x);
    a2 += bflo(v0.y) + bflo(v1.y) + bflo(v2.y) + bflo(v3.y);
    a3 += bfhi(v0.y) + bfhi(v1.y) + bfhi(v2.y) + bfhi(v3.y);
    e += 4;
  }
  for (; e < end; ++e) {
    const int s = adj16[e];
    const uint2 v = *(const uint2*)(T2b + (size_t)s * 64 + foff);
    a0 += bflo(v.x); a1 += bfhi(v.x); a2 += bflo(v.y); a3 += bfhi(v.y);
  }
  const int d = end - beg;
  const float inv = 1.0f / (float)(d > 1 ? d : 1);
  const float4 r = *(const float4*)(R2 + (size_t)n * 64 + foff);
  float4 o;
  o.x = a0 * inv + r.x;
  o.y = a1 * inv + r.y;
  o.z = a2 * inv + r.z;
  o.w = a3 * inv + r.w;
  *(float4*)(out + (size_t)n * 64 + foff) = o;
}

// ---------------- fused MFMA GEMM1+GEMM2, B staged in LDS (R10) ----------------
#define SP1 200
#define SP2 136
#define HP 136
__global__ __launch_bounds__(256) void gemm12_kernel(
    const uint16_t* __restrict__ AGGb, const uint16_t* __restrict__ xb,
    const uint16_t* __restrict__ S1t, const uint16_t* __restrict__ S2t,
    const float* __restrict__ b1, const float* __restrict__ b2,
    uint16_t* __restrict__ T2b, float* __restrict__ R2, int M) {
  __shared__ uint16_t BS[128 * SP1];
  __shared__ uint16_t Hs[64 * HP];
  const int tid = threadIdx.x;
  const int wv = tid >> 6;
  const int lane = tid & 63;
  const int m16 = lane & 15;
  const int quad = lane >> 4;
  const int rowBase = blockIdx.x * 64 + wv * 16;
  int arow = rowBase + m16;
  if (arow >= M) arow = M - 1;
  const int kq = quad * 8;

#pragma unroll
  for (int i = 0; i < 12; ++i) {
    const int idx8 = tid + i * 256;
    const int col = idx8 / 24;
    const int k8 = (idx8 - col * 24) * 8;
    const bf16x8 v = *(const bf16x8*)(S1t + (size_t)idx8 * 8);
    *(bf16x8*)&BS[col * SP1 + k8] = v;
  }
  bf16x8 a1f[6];
#pragma unroll
  for (int s = 0; s < 3; ++s)
    a1f[s] = *(const bf16x8*)(AGGb + (size_t)arow * IN_DIM + s * 32 + kq);
#pragma unroll
  for (int s = 0; s < 3; ++s)
    a1f[3 + s] = *(const bf16x8*)(xb + (size_t)arow * IN_DIM + s * 32 + kq);
  __syncthreads();

  f32x4 acc1[8];
#pragma unroll
  for (int cf = 0; cf < 8; ++cf) acc1[cf] = (f32x4){0.f, 0.f, 0.f, 0.f};
#pragma unroll
  for (int s = 0; s < 6; ++s) {
#pragma unroll
    for (int cf = 0; cf < 8; ++cf) {
      const bf16x8 b = *(const bf16x8*)&BS[(cf * 16 + m16) * SP1 + s * 32 + kq];
      acc1[cf] = __builtin_amdgcn_mfma_f32_16x16x32_bf16(a1f[s], b, acc1[cf], 0, 0, 0);
    }
  }

#pragma unroll
  for (int cf = 0; cf < 8; ++cf) {
    const int col = cf * 16 + m16;
    const float bias = b1[col];
#pragma unroll
    for (int r = 0; r < 4; ++r) {
      const float v = fmaxf(acc1[cf][r] + bias, 0.f);
      Hs[(wv * 16 + quad * 4 + r) * HP + col] = f2bf(v);
    }
  }
  __syncthreads();

#pragma unroll
  for (int i = 0; i < 8; ++i) {
    const int idx8 = tid + i * 256;
    const int col = idx8 >> 4;
    const int k8 = (idx8 & 15) * 8;
    const bf16x8 v = *(const bf16x8*)(S2t + (size_t)idx8 * 8);
    *(bf16x8*)&BS[col * SP2 + k8] = v;
  }
  __syncthreads();

  f32x4 acc2[8];
#pragma unroll
  for (int cf = 0; cf < 8; ++cf) acc2[cf] = (f32x4){0.f, 0.f, 0.f, 0.f};
#pragma unroll
  for (int s = 0; s < 4; ++s) {
    const bf16x8 a = *(const bf16x8*)&Hs[(wv * 16 + m16) * HP + s * 32 + kq];
#pragma unroll
    for (int cf = 0; cf < 8; ++cf) {
      const bf16x8 b = *(const bf16x8*)&BS[(cf * 16 + m16) * SP2 + s * 32 + kq];
      acc2[cf] = __builtin_amdgcn_mfma_f32_16x16x32_bf16(a, b, acc2[cf], 0, 0, 0);
    }
  }

#pragma unroll
  for (int cf = 0; cf < 8; ++cf) {
    const int col = cf * 16 + m16;
#pragma unroll
    for (int r = 0; r < 4; ++r) {
      const int row = rowBase + quad * 4 + r;
      if (row < M) {
        const float v = acc2[cf][r];
        if (col < 64) {
          T2b[(size_t)row * 64 + col] = f2bf(v);
        } else {
          R2[(size_t)row * 64 + (col - 64)] = v + b2[col - 64];
        }
      }
    }
  }
}

extern "C" void kernel_launch(void* const* d_in, const int* in_sizes, int n_in,
                              void* d_out, int out_size, void* d_ws, size_t ws_size,
                              hipStream_t stream) {
  const float* x   = (const float*)d_in[0];
  const int*   ei  = (const int*)d_in[1];
  const float* w1l = (const float*)d_in[2];
  const float* b1  = (const float*)d_in[3];
  const float* w1r = (const float*)d_in[4];
  const float* w2l = (const float*)d_in[5];
  const float* b2  = (const float*)d_in[6];
  const float* w2r = (const float*)d_in[7];
  float* out = (float*)d_out;

  const int N = in_sizes[0] / IN_DIM;   // 50000
  const int E = in_sizes[1] / 2;        // 800000
  const int* src = ei;
  const int* dst = ei + E;
  const int NB = (N + 255) >> 8;        // 196 buckets

  // ---- workspace carve (AGGb DISJOINT from T2b/R2 — round-7 bug) ----
  char* p = (char*)d_ws;
  uint16_t* AGGb = (uint16_t*)p; p += alignUp((size_t)N * IN_DIM * sizeof(uint16_t), 256);
  uint16_t* T2b  = (uint16_t*)p; p += alignUp((size_t)N * 64 * sizeof(uint16_t), 256);
  float* R2      = (float*)p;    p += alignUp((size_t)N * 64 * sizeof(float), 256);
  uint16_t* xb = (uint16_t*)p; p += alignUp((size_t)N * IN_DIM * sizeof(uint16_t), 256);
  uint16_t* S1t = (uint16_t*)p; p += alignUp(NS1 * sizeof(uint16_t), 256);
  uint16_t* S2t = (uint16_t*)p; p += alignUp(NS2 * sizeof(uint16_t), 256);
  int* rowptr = (int*)p; p += alignUp((size_t)(N + 1) * sizeof(int), 256);
  uint16_t* adj16 = (uint16_t*)p; p += alignUp((size_t)E * sizeof(uint16_t), 256);
  uint32_t* bucketBuf = (uint32_t*)p; p += alignUp((size_t)E * sizeof(uint32_t), 256);
  int* bucketPart = (int*)p;   p += alignUp(CNT_BLOCKS * 256 * sizeof(int), 256);
  int* bucketBase = (int*)p;   p += alignUp(257 * sizeof(int), 256);
  int* bucketCursor = (int*)p; p += alignUp(256 * sizeof(int), 256);
  (void)ws_size; (void)n_in; (void)out_size;

  const int total4 = N * IN_DIM / 4;
  const int prepThreads = NS1 + NS2 + total4;
  const int prepBlocks = (prepThreads + 255) / 256;
  count_prep_kernel<<<CNT_BLOCKS + prepBlocks, 256, 0, stream>>>(
      dst, bucketPart, E, x, w1l, w1r, w2l, w2r, S1t, S2t, xb, total4);
  bucket_scan_kernel<<<1, 256, 0, stream>>>(bucketPart, bucketBase, bucketCursor, rowptr, NB, N);
  bucket_scatter_kernel<<<(E + SCAT_CHUNK - 1) / SCAT_CHUNK, 256, 0, stream>>>(
      src, dst, bucketCursor, bucketBuf, E);
  bucket_build_kernel<<<NB, 256, 0, stream>>>(bucketBuf, bucketBase, rowptr, adj16, N);

  const int nodeBlocks16 = (N + 15) / 16;
  agg1_kernel<<<nodeBlocks16, 256, 0, stream>>>(xb, adj16, rowptr, AGGb, N);

  const int gemmBlocks = (N + 63) / 64;
  gemm12_kernel<<<gemmBlocks, 256, 0, stream>>>(AGGb, xb, S1t, S2t, b1, b2, T2b, R2, N);

  final_kernel<<<nodeBlocks16, 256, 0, stream>>>(T2b, R2, adj16, rowptr, out, N);
}